// Round 2
// 731.347 us; speedup vs baseline: 1.0627x; 1.0627x over previous
//
#include <hip/hip_runtime.h>

// ---------------------------------------------------------------------------
// FairnessBranch: router (BN->MLP->softmax) + 16 experts (BN folded ->
// D->128->64->1 sigmoid), weighted sum.  B=65536 D=1024 E=16.
//
// R5 = R4 hardened. Expert path: one [B x 2048] GEMM, 2 experts per block.
// 512-thread blocks, BM=BN=256, BK=32, ring-4 LDS (128KB), counted
// s_waitcnt vmcnt(12) pipeline (never drain-0 in main loop), s_setprio
// around MFMA cluster, bijective XCD swizzle. Layers 2/3 fused in-block
// (h1 reuses ring LDS; W2 frags read from L2).
// Hardening vs R4: __builtin_amdgcn_s_barrier() instead of raw asm
// s_barrier (convergent intrinsic, the m201-verified pattern), and
// __builtin_amdgcn_sched_barrier(0) after every counted s_waitcnt
// (rule #18: stop hipcc hoisting dependent LDS reads above the wait).
// prep kernels emit pre-swizzled linear-stage layouts:
//   xs_g  : [rb 256][step 32][m 256][32 k]  (16KB chunks, octet-XOR swz)
//   w1s   : [nt 8][step 32][h 256][32 k]    (h 0-127 = e0=2nt, 128-255 = e1)
//   rw1s  : [step 32][j 64][32 k]
// swizzle: phys_octet = logical_octet ^ ((row>>1)&3)  (row = m / h / j)
// ---------------------------------------------------------------------------

typedef unsigned short u16;
typedef __attribute__((ext_vector_type(8))) short bf16x8;
typedef __attribute__((ext_vector_type(4))) float f32x4;
typedef __attribute__((ext_vector_type(8))) unsigned short u16x8;
typedef __attribute__((ext_vector_type(4))) unsigned short u16x4;

#define MFMA16(a, b, c) __builtin_amdgcn_mfma_f32_16x16x32_bf16(a, b, c, 0, 0, 0)

#define B_ROWS 65536
#define NE 16
#define EPS 1e-5f

#define SBAR() __builtin_amdgcn_s_barrier()
#define VMCNT(n)                                             \
    do {                                                     \
        asm volatile("s_waitcnt vmcnt(" #n ")" ::: "memory");\
        __builtin_amdgcn_sched_barrier(0);                   \
    } while (0)

// fp32 -> bf16 round-to-nearest-even
__device__ inline u16 f2bf(float f) {
    union { float f; unsigned u; } c; c.f = f;
    unsigned u = c.u;
    return (u16)((u + 0x7fffu + ((u >> 16) & 1u)) >> 16);
}

// async global->LDS, 16B per lane. lds dest must be wave-uniform base.
__device__ inline void gload16(const u16* g, u16* s) {
    __builtin_amdgcn_global_load_lds(
        (const __attribute__((address_space(1))) unsigned int*)g,
        (__attribute__((address_space(3))) unsigned int*)s,
        16, 0, 0);
}

// ---------------------------------------------------------------------------
// prep bodies
// ---------------------------------------------------------------------------

// x [B][D] fp32 -> bf16 chunks [rb][step 32][m 256][32k swz].
// Block = 16 rows: dense 64KB read -> convert -> LDS (32KB, final image
// layout) -> 8 rounds of 1KB/wave contiguous global stores.
__device__ void body_prep_x(int blk, int tid, const float* __restrict__ x,
                            u16* __restrict__ xs_g, u16* __restrict__ lds) {
    int p = tid & 15, rloc = tid >> 4;          // 16 col-groups x 16 rows
    int r_g = blk * 16 + rloc;
    int lb = p & 7;
    int swz = (rloc >> 1) & 3;
    const float* xrow = x + (size_t)r_g * 1024;
#pragma unroll
    for (int i = 0; i < 8; ++i) {
        int kc = 2 * i + (p >> 3);
        int c = kc * 64 + lb * 8;               // k0 (multiple of 8)
        float4 f0 = *(const float4*)(xrow + c);
        float4 f1 = *(const float4*)(xrow + c + 4);
        u16x8 u;
        u[0] = f2bf(f0.x); u[1] = f2bf(f0.y); u[2] = f2bf(f0.z); u[3] = f2bf(f0.w);
        u[4] = f2bf(f1.x); u[5] = f2bf(f1.y); u[6] = f2bf(f1.z); u[7] = f2bf(f1.w);
        int s = c >> 5;                         // step chunk 0..31
        int q = (c >> 3) & 3;                   // logical octet
        *(u16x8*)&lds[s * 512 + rloc * 32 + ((q ^ swz) << 3)] = u;
    }
    __syncthreads();
    int rb = blk >> 4, m0 = (blk & 15) * 16;
    int lane = tid & 63, th = tid >> 6;
#pragma unroll
    for (int j = 0; j < 8; ++j) {
        int c = j * 4 + th;                     // chunk 0..31
        u16x8 v = *(const u16x8*)&lds[c * 512 + lane * 8];
        *(u16x8*)&xs_g[((size_t)(rb * 32 + c) << 13) + m0 * 32 + lane * 8] = v;
    }
}

// W1_eff^T bf16: w1s[nt][step][h 256][32k swz]
__device__ void body_prep_w1s(int t, const float* __restrict__ eW1, const float* __restrict__ eg,
                              const float* __restrict__ ev, u16* __restrict__ w1s) {
    int qp = t & 3, h = (t >> 2) & 255, s = (t >> 10) & 31, nt = t >> 15;
    int q = qp ^ ((h >> 1) & 3);
    int e = nt * 2 + (h >> 7), hl = h & 127;
    int k0 = s * 32 + q * 8;
    u16x8 u;
#pragma unroll
    for (int j = 0; j < 8; ++j) {
        int d = k0 + j;
        float sc = eg[e * 1024 + d] * rsqrtf(ev[e * 1024 + d] + EPS);
        u[j] = f2bf(eW1[((size_t)e * 1024 + d) * 128 + hl] * sc);
    }
    *(u16x8*)&w1s[((size_t)(nt * 32 + s) << 13) + h * 32 + qp * 8] = u;
}

// b1_eff[e][h] = eb1 + sum_d shift[e][d]*eW1[e][d][h]; one wave per (e,h)
__device__ void body_prep_b1(int g, int lane, const float* __restrict__ eW1,
                             const float* __restrict__ eg, const float* __restrict__ eb,
                             const float* __restrict__ em, const float* __restrict__ ev,
                             const float* __restrict__ eb1, float* __restrict__ b1e) {
    int e = g >> 7, h = g & 127;
    float s = 0.f;
    for (int d = lane; d < 1024; d += 64) {
        float sc = eg[e * 1024 + d] * rsqrtf(ev[e * 1024 + d] + EPS);
        float sh = eb[e * 1024 + d] - em[e * 1024 + d] * sc;
        s += sh * eW1[((size_t)e * 1024 + d) * 128 + h];
    }
#pragma unroll
    for (int m = 1; m < 64; m <<= 1) s += __shfl_xor(s, m, 64);
    if (lane == 0) b1e[e * 128 + h] = eb1[e * 128 + h] + s;
}

// router W1_eff^T bf16: rw1s[step][j 64][32k swz]
__device__ void body_prep_rw1s(int t, const float* __restrict__ rW1, const float* __restrict__ rg,
                               const float* __restrict__ rv, u16* __restrict__ rw1s) {
    int qp = t & 3, jj = (t >> 2) & 63, s = t >> 8;   // s 0..31
    int q = qp ^ ((jj >> 1) & 3);
    int k0 = s * 32 + q * 8;
    u16x8 u;
#pragma unroll
    for (int k = 0; k < 8; ++k) {
        int d = k0 + k;
        float sc = rg[d] * rsqrtf(rv[d] + EPS);
        u[k] = f2bf(rW1[d * 64 + jj] * sc);
    }
    *(u16x8*)&rw1s[(s << 11) + jj * 32 + qp * 8] = u;
}

// rb1_eff[j] = rb1[j] + sum_d shift[d]*rW1[d][j]; one wave per j
__device__ void body_prep_rb1(int j, int lane, const float* __restrict__ rW1,
                              const float* __restrict__ rg, const float* __restrict__ rbta,
                              const float* __restrict__ rm, const float* __restrict__ rv,
                              const float* __restrict__ rb1, float* __restrict__ rb1e) {
    float s = 0.f;
    for (int d = lane; d < 1024; d += 64) {
        float sc = rg[d] * rsqrtf(rv[d] + EPS);
        float sh = rbta[d] - rm[d] * sc;
        s += sh * rW1[d * 64 + j];
    }
#pragma unroll
    for (int m = 1; m < 64; m <<= 1) s += __shfl_xor(s, m, 64);
    if (lane == 0) rb1e[j] = rb1[j] + s;
}

// W2^T bf16: w2s[e][j(64)][128 swizzled]  (read as frags straight from L2)
__device__ void body_prep_w2s(int t, const float* __restrict__ eW2, u16* __restrict__ w2s) {
    int p = t & 15, j = (t >> 4) & 63, e = t >> 10;
    int lb = p ^ (j & 7);
    int h0 = lb * 8;
    u16x8 u;
#pragma unroll
    for (int jj = 0; jj < 8; ++jj)
        u[jj] = f2bf(eW2[((size_t)e * 128 + h0 + jj) * 64 + j]);
    *(u16x8*)&w2s[((e * 64 + j) << 7) + p * 8] = u;
}

// grid layout: [0,4096) prep_x | [4096,5120) w1s | [5120,5632) b1
//              [5632,5664) rw1s | [5664,5680) rb1 | [5680,5744) w2s
__global__ __launch_bounds__(256) void prep_all(
    const float* __restrict__ x, u16* __restrict__ xs_g,
    const float* __restrict__ eW1, const float* __restrict__ eg,
    const float* __restrict__ eb, const float* __restrict__ em,
    const float* __restrict__ ev, const float* __restrict__ eb1,
    u16* __restrict__ w1s, float* __restrict__ b1e,
    const float* __restrict__ rW1, const float* __restrict__ rg,
    const float* __restrict__ rbta, const float* __restrict__ rm,
    const float* __restrict__ rv, const float* __restrict__ rb1,
    u16* __restrict__ rw1s, float* __restrict__ rb1e,
    const float* __restrict__ eW2, u16* __restrict__ w2s) {
    __shared__ __align__(16) u16 lds[16384];   // 32KB bounce buffer (prep_x only)
    int bid = blockIdx.x, tid = threadIdx.x;
    if (bid < 4096) {
        body_prep_x(bid, tid, x, xs_g, lds);
    } else if (bid < 5120) {
        body_prep_w1s((bid - 4096) * 256 + tid, eW1, eg, ev, w1s);
    } else if (bid < 5632) {
        body_prep_b1((bid - 5120) * 4 + (tid >> 6), tid & 63, eW1, eg, eb, em, ev, eb1, b1e);
    } else if (bid < 5664) {
        body_prep_rw1s((bid - 5632) * 256 + tid, rW1, rg, rv, rw1s);
    } else if (bid < 5680) {
        body_prep_rb1((bid - 5664) * 4 + (tid >> 6), tid & 63, rW1, rg, rbta, rm, rv, rb1, rb1e);
    } else {
        body_prep_w2s((bid - 5680) * 256 + tid, eW2, w2s);
    }
}

// ---------------------------------------------------------------------------
// fused main: blocks [0,256) router (256 rows each), [256,2304) experts
// (256 rows x 2 experts each). 512 threads, 128KB LDS, 1 block/CU.
// ---------------------------------------------------------------------------
__global__ __launch_bounds__(512, 2) void fused_main(
    const u16* __restrict__ xs_g, const u16* __restrict__ w1s,
    const float* __restrict__ b1e, const u16* __restrict__ w2s,
    const float* __restrict__ eb2, const float* __restrict__ eW3,
    const float* __restrict__ eb3, float* __restrict__ out_eo,
    const u16* __restrict__ rw1s, const float* __restrict__ rb1e,
    const float* __restrict__ rW2, const float* __restrict__ rb2,
    const float* __restrict__ rW3, const float* __restrict__ rb3,
    float* __restrict__ out_rw) {
    __shared__ __align__(16) char smem[131072];

    int tid = threadIdx.x;
    int wave = tid >> 6, lane = tid & 63, quad = lane >> 4, l15 = lane & 15;
    int phq = (quad ^ ((l15 >> 1) & 3)) * 8;     // swizzled k-octet offset (u16)

    if (blockIdx.x >= 256) {
        // ------------------------- expert path -------------------------
        // bijective XCD swizzle: XCD x gets rb in [x*32, x*32+32) x all nt.
        int i = blockIdx.x - 256;
        int rb = (i & 7) * 32 + ((i >> 3) >> 3);
        int nt = (i >> 3) & 7;
        int wm = wave >> 2, wn = wave & 3;       // wm: h-half(expert), wn: m-quarter

        u16* ring = (u16*)smem;                  // 4 slots x 16384 u16 (A 16KB | B 16KB)
        const u16* gA = w1s + ((size_t)nt << 18);
        const u16* gB = xs_g + ((size_t)rb << 18);

        f32x4 acc[8][4] = {};

        auto STAGE = [&](int t) {
            u16* ls = ring + (t & 3) * 16384 + wave * 1024;
            const u16* ga = gA + (t << 13) + wave * 1024;
            const u16* gb = gB + (t << 13) + wave * 1024;
            gload16(ga + lane * 8, ls);
            gload16(ga + 512 + lane * 8, ls + 512);
            gload16(gb + lane * 8, ls + 8192);
            gload16(gb + 512 + lane * 8, ls + 8192 + 512);
        };
        auto COMPUTE = [&](int t) {
            const u16* lA = ring + (t & 3) * 16384;
            const u16* lB = lA + 8192;
            bf16x8 a[8], b[4];
#pragma unroll
            for (int ii = 0; ii < 8; ++ii)
                a[ii] = *(const bf16x8*)&lA[(wm * 128 + ii * 16 + l15) * 32 + phq];
#pragma unroll
            for (int jj = 0; jj < 4; ++jj)
                b[jj] = *(const bf16x8*)&lB[(wn * 64 + jj * 16 + l15) * 32 + phq];
            __builtin_amdgcn_s_setprio(1);
#pragma unroll
            for (int ii = 0; ii < 8; ++ii)
#pragma unroll
                for (int jj = 0; jj < 4; ++jj)
                    acc[ii][jj] = MFMA16(a[ii], b[jj], acc[ii][jj]);
            __builtin_amdgcn_s_setprio(0);
        };

        // ring-4 pipeline: 3 steps (12 loads) in flight, counted vmcnt.
        STAGE(0); STAGE(1); STAGE(2);
#pragma clang loop unroll(disable)
        for (int s = 0; s < 29; ++s) {
            SBAR();                               // slot (s-1) reads finished
            STAGE(s + 3);                         // -> slot (s-1)&3
            VMCNT(12);                            // step s landed (this wave)
            SBAR();                               // all waves' step-s data landed
            COMPUTE(s);
        }
        SBAR(); VMCNT(8); SBAR(); COMPUTE(29);
        SBAR(); VMCNT(4); SBAR(); COMPUTE(30);
        SBAR(); VMCNT(0); SBAR(); COMPUTE(31);

        // ---- epilogue: h1 = relu(acc+b1) bf16 into ring (256x256, swz) ----
        int e = nt * 2 + wm;
        u16* h1 = ring;
        SBAR();                                   // all step-31 reads done
#pragma unroll
        for (int ii = 0; ii < 8; ++ii) {
            float4 bv = *(const float4*)&b1e[e * 128 + ii * 16 + quad * 4];
            float bva[4] = {bv.x, bv.y, bv.z, bv.w};
            int h0 = wm * 128 + ii * 16 + quad * 4;
            int oc = h0 >> 3, hin = h0 & 7;
#pragma unroll
            for (int jj = 0; jj < 4; ++jj) {
                int m = wn * 64 + jj * 16 + l15;
                u16x4 pk;
#pragma unroll
                for (int r = 0; r < 4; ++r)
                    pk[r] = f2bf(fmaxf(acc[ii][jj][r] + bva[r], 0.f));
                int poc = (oc & 24) | ((oc ^ m) & 7);
                *(u16x4*)&h1[m * 256 + poc * 8 + hin] = pk;
            }
        }
        // W2 fragments straight from global (L2-hot, 16KB/expert)
        bf16x8 w2f[4][4];
        const u16* gW2 = w2s + e * 8192;
#pragma unroll
        for (int ks = 0; ks < 4; ++ks)
#pragma unroll
            for (int tj = 0; tj < 4; ++tj) {
                int jc = tj * 16 + l15;
                int pq = (ks * 4 + quad) ^ (jc & 7);
                w2f[ks][tj] = *(const bf16x8*)&gW2[jc * 128 + pq * 8];
            }
        asm volatile("s_waitcnt lgkmcnt(0)" ::: "memory");  // h1 ds_writes done
        __builtin_amdgcn_sched_barrier(0);
        SBAR();

        // ---- layer 2: C2[m][j] = h1[m][:].W2[:,j], wave = (expert wm, rows wn)
        f32x4 acc2[4][4] = {};
#pragma unroll
        for (int ks = 0; ks < 4; ++ks) {
            bf16x8 a2[4];
#pragma unroll
            for (int mi = 0; mi < 4; ++mi) {
                int m = wn * 64 + mi * 16 + l15;
                int oc2 = wm * 16 + ks * 4 + quad;
                int poc2 = (oc2 & 24) | ((oc2 ^ m) & 7);
                a2[mi] = *(const bf16x8*)&h1[m * 256 + poc2 * 8];
            }
#pragma unroll
            for (int mi = 0; mi < 4; ++mi)
#pragma unroll
                for (int tj = 0; tj < 4; ++tj)
                    acc2[mi][tj] = MFMA16(a2[mi], w2f[ks][tj], acc2[mi][tj]);
        }

        // ---- layer 3 + sigmoid ----
        float b2v[4], w3v[4];
#pragma unroll
        for (int tj = 0; tj < 4; ++tj) {
            int jc = tj * 16 + l15;
            b2v[tj] = eb2[e * 64 + jc];
            w3v[tj] = eW3[e * 64 + jc];
        }
        float be3 = eb3[e];
#pragma unroll
        for (int mi = 0; mi < 4; ++mi) {
            float sv[4] = {0.f, 0.f, 0.f, 0.f};
#pragma unroll
            for (int tj = 0; tj < 4; ++tj)
#pragma unroll
                for (int r = 0; r < 4; ++r)
                    sv[r] += fmaxf(acc2[mi][tj][r] + b2v[tj], 0.f) * w3v[tj];
#pragma unroll
            for (int mask = 1; mask < 16; mask <<= 1)
#pragma unroll
                for (int r = 0; r < 4; ++r) sv[r] += __shfl_xor(sv[r], mask, 64);
            if (l15 == 0) {
#pragma unroll
                for (int r = 0; r < 4; ++r) {
                    int m = wn * 64 + mi * 16 + quad * 4 + r;
                    float z = sv[r] + be3;
                    out_eo[(size_t)(rb * 256 + m) * 16 + e] = 1.f / (1.f + __expf(-z));
                }
            }
        }
    } else {
        // ------------------------- router path -------------------------
        int rb = blockIdx.x;
        u16* ldsX = (u16*)smem;                  // 2 x 8192 u16 (two steps)
        u16* ldsW = (u16*)smem + 16384;          // 2 x 2048 u16
        float* h_r = (float*)smem;               // [256][68] fp32 (after K-loop)
        float* h2s = (float*)(smem + 69632);     // [256][36] fp32
        const u16* gB = xs_g + ((size_t)rb << 18);

        f32x4 accr[4][2] = {};
        for (int kt = 0; kt < 16; ++kt) {
            const u16* gx = gB + ((size_t)(2 * kt) << 13) + wave * 1024;
            const u16* gw = rw1s + ((2 * kt) << 11) + wave * 512;
            u16* lx = ldsX + wave * 1024;
            gload16(gx + lane * 8, lx);
            gload16(gx + 512 + lane * 8, lx + 512);
            gload16(gx + 8192 + lane * 8, lx + 8192);
            gload16(gx + 8192 + 512 + lane * 8, lx + 8192 + 512);
            gload16(gw + lane * 8, ldsW + wave * 512);
            __syncthreads();
#pragma unroll
            for (int st = 0; st < 2; ++st) {
                bf16x8 aw[4], bx[2];
#pragma unroll
                for (int jf = 0; jf < 4; ++jf)
                    aw[jf] = *(const bf16x8*)&ldsW[st * 2048 + (jf * 16 + l15) * 32 + phq];
#pragma unroll
                for (int mf = 0; mf < 2; ++mf)
                    bx[mf] = *(const bf16x8*)&ldsX[st * 8192 + (wave * 32 + mf * 16 + l15) * 32 + phq];
#pragma unroll
                for (int jf = 0; jf < 4; ++jf)
#pragma unroll
                    for (int mf = 0; mf < 2; ++mf)
                        accr[jf][mf] = MFMA16(aw[jf], bx[mf], accr[jf][mf]);
            }
            __syncthreads();
        }

        // epilogue: h_r[m][j] fp32 (stride 68)
#pragma unroll
        for (int jf = 0; jf < 4; ++jf) {
            int j0 = jf * 16 + quad * 4;
            float4 bv = *(const float4*)&rb1e[j0];
#pragma unroll
            for (int mf = 0; mf < 2; ++mf) {
                int m = wave * 32 + mf * 16 + l15;
                float4 hv;
                hv.x = fmaxf(accr[jf][mf][0] + bv.x, 0.f);
                hv.y = fmaxf(accr[jf][mf][1] + bv.y, 0.f);
                hv.z = fmaxf(accr[jf][mf][2] + bv.z, 0.f);
                hv.w = fmaxf(accr[jf][mf][3] + bv.w, 0.f);
                *(float4*)&h_r[m * 68 + j0] = hv;
            }
        }
        __syncthreads();

        // layer 2 (64->32), fp32 VALU
        {
            int m = tid & 255, qg = tid >> 8;
            float h2r[16];
#pragma unroll
            for (int k = 0; k < 16; ++k) h2r[k] = 0.f;
            for (int i2 = 0; i2 < 64; ++i2) {
                float hv = h_r[m * 68 + i2];
                const float4* wrow = (const float4*)&rW2[i2 * 32 + qg * 16];
                float w[16];
                *(float4*)&w[0] = wrow[0];
                *(float4*)&w[4] = wrow[1];
                *(float4*)&w[8] = wrow[2];
                *(float4*)&w[12] = wrow[3];
#pragma unroll
                for (int k = 0; k < 16; ++k) h2r[k] += hv * w[k];
            }
#pragma unroll
            for (int k = 0; k < 16; ++k)
                h2r[k] = fmaxf(h2r[k] + rb2[qg * 16 + k], 0.f);
#pragma unroll
            for (int k = 0; k < 16; k += 4)
                *(float4*)&h2s[m * 36 + qg * 16 + k] = *(float4*)&h2r[k];
        }
        __syncthreads();

        // layer 3 (32->16) + softmax
        if (tid < 256) {
            int mm = tid;
            float lg[16];
#pragma unroll
            for (int o = 0; o < 16; ++o) lg[o] = 0.f;
            for (int q = 0; q < 32; ++q) {
                float hv = h2s[mm * 36 + q];
                const float4* wr = (const float4*)&rW3[q * 16];
                float w[16];
                *(float4*)&w[0] = wr[0];
                *(float4*)&w[4] = wr[1];
                *(float4*)&w[8] = wr[2];
                *(float4*)&w[12] = wr[3];
#pragma unroll
                for (int o = 0; o < 16; ++o) lg[o] += hv * w[o];
            }
#pragma unroll
            for (int o = 0; o < 16; ++o) lg[o] += rb3[o];
            float mx = lg[0];
#pragma unroll
            for (int o = 1; o < 16; ++o) mx = fmaxf(mx, lg[o]);
            float ss = 0.f;
#pragma unroll
            for (int o = 0; o < 16; ++o) { lg[o] = __expf(lg[o] - mx); ss += lg[o]; }
            float inv = 1.f / ss;
            size_t base = (size_t)(rb * 256 + mm) * 16;
#pragma unroll
            for (int o = 0; o < 16; o += 4) {
                float4 v;
                v.x = lg[o] * inv; v.y = lg[o + 1] * inv;
                v.z = lg[o + 2] * inv; v.w = lg[o + 3] * inv;
                *(float4*)&out_rw[base + o] = v;
            }
        }
    }
}

// weighted_pred[b] = sum_e rw[b][e]*eo[b][e]
__global__ void combine_kernel(const float* __restrict__ rw, const float* __restrict__ eo,
                               float* __restrict__ wp) {
    int b = blockIdx.x * 256 + threadIdx.x;
    const float4* r4 = (const float4*)(rw + (size_t)b * 16);
    const float4* o4 = (const float4*)(eo + (size_t)b * 16);
    float s = 0.f;
#pragma unroll
    for (int k = 0; k < 4; ++k) {
        float4 r = r4[k], o = o4[k];
        s += r.x * o.x + r.y * o.y + r.z * o.z + r.w * o.w;
    }
    wp[b] = s;
}

// ---------------------------------------------------------------------------

extern "C" void kernel_launch(void* const* d_in, const int* in_sizes, int n_in,
                              void* d_out, int out_size, void* d_ws, size_t ws_size,
                              hipStream_t stream) {
    const float* x       = (const float*)d_in[0];
    const float* r_gamma = (const float*)d_in[1];
    const float* r_beta  = (const float*)d_in[2];
    const float* r_mean  = (const float*)d_in[3];
    const float* r_var   = (const float*)d_in[4];
    const float* rW1     = (const float*)d_in[5];
    const float* rb1     = (const float*)d_in[6];
    const float* rW2     = (const float*)d_in[7];
    const float* rb2     = (const float*)d_in[8];
    const float* rW3     = (const float*)d_in[9];
    const float* rb3     = (const float*)d_in[10];
    const float* e_gamma = (const float*)d_in[11];
    const float* e_beta  = (const float*)d_in[12];
    const float* e_mean  = (const float*)d_in[13];
    const float* e_var   = (const float*)d_in[14];
    const float* eW1     = (const float*)d_in[15];
    const float* eb1     = (const float*)d_in[16];
    const float* eW2     = (const float*)d_in[17];
    const float* eb2     = (const float*)d_in[18];
    const float* eW3     = (const float*)d_in[19];
    const float* eb3     = (const float*)d_in[20];

    char* ws = (char*)d_ws;
    u16* xs_g   = (u16*)ws;                          // 134217728 B
    u16* w1s    = (u16*)(ws + 134217728);            // 4194304 B
    u16* rw1s   = (u16*)(ws + 138412032);            // 131072 B
    u16* w2s    = (u16*)(ws + 138543104);            // 262144 B
    float* b1e  = (float*)(ws + 138805248);          // 8192 B
    float* rb1e = (float*)(ws + 138813440);          // 256 B

    float* out_wp = (float*)d_out;
    float* out_rw = out_wp + B_ROWS;
    float* out_eo = out_rw + (size_t)B_ROWS * NE;

    prep_all<<<5744, 256, 0, stream>>>(
        x, xs_g,
        eW1, e_gamma, e_beta, e_mean, e_var, eb1, w1s, b1e,
        rW1, r_gamma, r_beta, r_mean, r_var, rb1, rw1s, rb1e,
        eW2, w2s);

    fused_main<<<2304, 512, 0, stream>>>(
        xs_g, w1s, b1e, w2s, eb2, eW3, eb3, out_eo,
        rw1s, rb1e, rW2, rb2, rW3, rb3, out_rw);

    combine_kernel<<<256, 256, 0, stream>>>(out_rw, out_eo, out_wp);
}